// Round 1
// baseline (767.177 us; speedup 1.0000x reference)
//
#include <hip/hip_runtime.h>
#include <math.h>

#define B 256
#define S 50
#define D 32
#define V 10000
#define KK 16
#define HH 64
#define LL 2
#define UU 32
#define TT 30          // trigger_seq_length
#define NROWS (B*S)    // 12800
#define NORMC 0.01f

__device__ __forceinline__ float sigmoidf_(float x) { return 1.0f / (1.0f + expf(-x)); }

// ---------------- tnorm[v] = 0.5*||embd[v]||^2 ----------------
__global__ __launch_bounds__(256) void k_tnorm(const float* __restrict__ embd,
                                               float* __restrict__ tnorm) {
    int v = blockIdx.x * 256 + threadIdx.x;
    if (v >= V) return;
    float s = 0.f;
#pragma unroll
    for (int j = 0; j < 8; j++) {
        float4 e4 = *(const float4*)(embd + (size_t)v * D + 4 * j);
        s += e4.x * e4.x + e4.y * e4.y + e4.z * e4.z + e4.w * e4.w;
    }
    tnorm[v] = 0.5f * s;
}

// ---------------- VQ argmin: score = 0.5*||t||^2 - q.t ----------------
// Block: 256 threads, 32 rows, half of V (5000 codes), chunks of 256 codes in LDS.
// Thread tile: 4 rows x 8 codes.
#define VQ_R 32
#define VQ_C 256
#define VQ_HALF 5000

__global__ __launch_bounds__(256) void k_vq(const float* __restrict__ z1,
                                            const float* __restrict__ embd,
                                            const float* __restrict__ tnorm,
                                            float* __restrict__ pb_s,
                                            int* __restrict__ pb_v) {
    __shared__ float qT[32][36];    // [d][row], pad 36: conflict-free b128 reads
    __shared__ float eT[32][260];   // [d][code], pad 260
    __shared__ float red_s[32][33];
    __shared__ int   red_v[32][33];
    const int tid = threadIdx.x;
    const int rb = blockIdx.x >> 1;
    const int half = blockIdx.x & 1;
    const int row0 = rb * VQ_R;
    {   // stage q rows transposed: 32 rows x 32 d = 256 float4, 1/thread
        int r = tid >> 3, d4 = (tid & 7) * 4;
        float4 q4 = *(const float4*)(z1 + (size_t)(row0 + r) * D + d4);
        qT[d4 + 0][r] = q4.x; qT[d4 + 1][r] = q4.y;
        qT[d4 + 2][r] = q4.z; qT[d4 + 3][r] = q4.w;
    }
    const int rg = tid & 7;    // rows 4*rg..4*rg+3
    const int vg = tid >> 3;   // codes 8*vg..8*vg+7 within chunk
    float best[4]; int bestv[4];
#pragma unroll
    for (int i = 0; i < 4; i++) { best[i] = INFINITY; bestv[i] = 0; }
    const int vbeg = half * VQ_HALF, vend = vbeg + VQ_HALF;
    for (int v0 = vbeg; v0 < vend; v0 += VQ_C) {
        __syncthreads();
#pragma unroll
        for (int i = 0; i < 8; i++) {   // stage 256 codes x 32 d, transposed
            int p = tid + i * 256;
            int vl = p >> 3, d4 = (p & 7) * 4;
            int v = v0 + vl;
            float4 e4 = make_float4(0.f, 0.f, 0.f, 0.f);
            if (v < vend) e4 = *(const float4*)(embd + (size_t)v * D + d4);
            eT[d4 + 0][vl] = e4.x; eT[d4 + 1][vl] = e4.y;
            eT[d4 + 2][vl] = e4.z; eT[d4 + 3][vl] = e4.w;
        }
        __syncthreads();
        float acc[4][8];
#pragma unroll
        for (int ri = 0; ri < 4; ri++)
#pragma unroll
            for (int vi = 0; vi < 8; vi++) acc[ri][vi] = 0.f;
#pragma unroll
        for (int d = 0; d < 32; d++) {
            float4 a  = *(const float4*)&qT[d][4 * rg];
            float4 b0 = *(const float4*)&eT[d][8 * vg];
            float4 b1 = *(const float4*)&eT[d][8 * vg + 4];
            float av[4] = {a.x, a.y, a.z, a.w};
            float bv[8] = {b0.x, b0.y, b0.z, b0.w, b1.x, b1.y, b1.z, b1.w};
#pragma unroll
            for (int ri = 0; ri < 4; ri++)
#pragma unroll
                for (int vi = 0; vi < 8; vi++)
                    acc[ri][vi] = fmaf(av[ri], bv[vi], acc[ri][vi]);
        }
#pragma unroll
        for (int vi = 0; vi < 8; vi++) {
            int v = v0 + 8 * vg + vi;
            if (v < vend) {
                float tn = tnorm[v];
#pragma unroll
                for (int ri = 0; ri < 4; ri++) {
                    float sc = tn - acc[ri][vi];
                    if (sc < best[ri]) { best[ri] = sc; bestv[ri] = v; }
                }
            }
        }
    }
    __syncthreads();
#pragma unroll
    for (int ri = 0; ri < 4; ri++) {
        red_s[4 * rg + ri][vg] = best[ri];
        red_v[4 * rg + ri][vg] = bestv[ri];
    }
    __syncthreads();
    if (tid < 32) {
        float bs = INFINITY; int bv = 0x7fffffff;
        for (int j = 0; j < 32; j++) {
            float s = red_s[tid][j]; int v = red_v[tid][j];
            if (s < bs || (s == bs && v < bv)) { bs = s; bv = v; }
        }
        pb_s[(size_t)(row0 + tid) * 2 + half] = bs;
        pb_v[(size_t)(row0 + tid) * 2 + half] = bv;
    }
}

// ---------------- gather z_emb, VQ loss, decoder (s<=TT only) ----------------
__global__ __launch_bounds__(256) void k_gather(const float* __restrict__ z2,
                                                const float* __restrict__ embd,
                                                const float* __restrict__ pb_s,
                                                const int* __restrict__ pb_v,
                                                const float* __restrict__ dw1,
                                                const float* __restrict__ db1,
                                                const float* __restrict__ dw2,
                                                const float* __restrict__ db2,
                                                float* __restrict__ z_recon,
                                                float* __restrict__ loss_sum) {
    int row = blockIdx.x * 256 + threadIdx.x;  // 0..12799
    float s0 = pb_s[row * 2], s1 = pb_s[row * 2 + 1];
    int v0 = pb_v[row * 2], v1 = pb_v[row * 2 + 1];
    int vid = (s1 < s0 || (s1 == s0 && v1 < v0)) ? v1 : v0;
    const float* ze = embd + (size_t)vid * D;
    float zer[32];
#pragma unroll
    for (int j = 0; j < 8; j++) {
        float4 e4 = *(const float4*)(ze + 4 * j);
        zer[4 * j] = e4.x; zer[4 * j + 1] = e4.y; zer[4 * j + 2] = e4.z; zer[4 * j + 3] = e4.w;
    }
    float ls = 0.f;
#pragma unroll
    for (int j = 0; j < 8; j++) {
        float4 x4 = *(const float4*)(z2 + (size_t)row * D + 4 * j);
        float d0 = x4.x - zer[4 * j], d1 = x4.y - zer[4 * j + 1];
        float d2 = x4.z - zer[4 * j + 2], d3 = x4.w - zer[4 * j + 3];
        ls += d0 * d0 + d1 * d1 + d2 * d2 + d3 * d3;
    }
#pragma unroll
    for (int off = 32; off > 0; off >>= 1) ls += __shfl_down(ls, off);
    if ((threadIdx.x & 63) == 0) atomicAdd(loss_sum, ls);
    int s = row % S;
    if (s <= TT) {
        int b = row / S;
        float zr[32];
#pragma unroll
        for (int d = 0; d < 32; d++) zr[d] = db2[d];
        for (int h = 0; h < 64; h++) {
            float a = db1[h];
#pragma unroll
            for (int d = 0; d < 32; d++) a = fmaf(zer[d], dw1[d * 64 + h], a);
            a = (a >= 0.f) ? a : 0.1f * a;  // leaky_relu 0.1
#pragma unroll
            for (int d = 0; d < 32; d++) zr[d] = fmaf(a, dw2[h * 32 + d], zr[d]);
        }
        float* outp = z_recon + (size_t)b * ((TT + 1) * D) + s * D;
#pragma unroll
        for (int d = 0; d < 32; d++) outp[d] = zr[d];
    }
}

// ---------------- GRU (31 steps) + output MLP; 512 blocks: [gru][sample] ----------------
__global__ __launch_bounds__(128) void k_gru(const float* __restrict__ z_recon,
                                             const float* __restrict__ z2,
                                             const float* __restrict__ i_wih, const float* __restrict__ i_whh,
                                             const float* __restrict__ i_bih, const float* __restrict__ i_bhh,
                                             const float* __restrict__ c_wih, const float* __restrict__ c_whh,
                                             const float* __restrict__ c_bih, const float* __restrict__ c_bhh,
                                             const float* __restrict__ im_w1, const float* __restrict__ im_b1,
                                             const float* __restrict__ im_w2, const float* __restrict__ im_b2,
                                             const float* __restrict__ cm_w1, const float* __restrict__ cm_b1,
                                             const float* __restrict__ cm_w2, const float* __restrict__ cm_b2,
                                             float* __restrict__ z1f, float* __restrict__ z2f) {
    const int tid = threadIdx.x;
    const int which = blockIdx.x >> 8;
    const int b = blockIdx.x & 255;
    const float* x; int xstride;
    const float *wih, *whh, *bih, *bhh, *w1, *b1, *w2, *b2; float* zf;
    if (which == 0) { x = z_recon; xstride = (TT + 1) * D; wih = i_wih; whh = i_whh; bih = i_bih; bhh = i_bhh; w1 = im_w1; b1 = im_b1; w2 = im_w2; b2 = im_b2; zf = z1f; }
    else            { x = z2;      xstride = S * D;        wih = c_wih; whh = c_whh; bih = c_bih; bhh = c_bhh; w1 = cm_w1; b1 = cm_b1; w2 = cm_w2; b2 = cm_b2; zf = z2f; }
    __shared__ float wihT[32][97];  // [d][e] pad 97 -> conflict-free
    __shared__ float whhT[32][97];
    __shared__ float gi[TT + 1][96];
    __shared__ float xs[TT + 1][32];
    __shared__ float hsh[32];
    __shared__ float gh[96];
    __shared__ float bh2[96];
    __shared__ float af[32];
    for (int p = tid; p < 96 * 32; p += 128) {
        int e = p >> 5, d = p & 31;
        wihT[d][e] = wih[p];
        whhT[d][e] = whh[p];
    }
    for (int p = tid; p < (TT + 1) * D; p += 128) xs[p >> 5][p & 31] = x[(size_t)b * xstride + p];
    if (tid < 96) bh2[tid] = bhh[tid];
    if (tid < 32) hsh[tid] = 0.f;
    __syncthreads();
    for (int p = tid; p < (TT + 1) * 96; p += 128) {
        int s = p / 96, e = p % 96;
        float g = bih[e];
#pragma unroll
        for (int d = 0; d < 32; d++) g = fmaf(xs[s][d], wihT[d][e], g);
        gi[s][e] = g;
    }
    __syncthreads();
    for (int t = 0; t <= TT; t++) {
        if (tid < 96) {
            float g = bh2[tid];
#pragma unroll
            for (int d = 0; d < 32; d++) g = fmaf(hsh[d], whhT[d][tid], g);
            gh[tid] = g;
        }
        __syncthreads();
        float hn = 0.f;
        if (tid < 32) {
            float rr = sigmoidf_(gi[t][tid] + gh[tid]);
            float zz = sigmoidf_(gi[t][tid + 32] + gh[tid + 32]);
            float nn = tanhf(gi[t][tid + 64] + rr * gh[tid + 64]);
            hn = (1.f - zz) * nn + zz * hsh[tid];
        }
        __syncthreads();
        if (tid < 32) hsh[tid] = hn;
        __syncthreads();
    }
    if (tid < 32) {
        float a = b1[tid];
#pragma unroll
        for (int d = 0; d < 32; d++) a = fmaf(hsh[d], w1[d * 32 + tid], a);
        af[tid] = tanhf(a);
    }
    __syncthreads();
    if (tid < 32) {
        float o = b2[tid];
#pragma unroll
        for (int d = 0; d < 32; d++) o = fmaf(af[d], w2[d * 32 + tid], o);
        zf[(size_t)b * 32 + tid] = o;
    }
}

// ---------------- hypernetwork epilogue + loss write ----------------
__global__ __launch_bounds__(64) void k_hyper(const float* __restrict__ x1,
                                              const float* __restrict__ z1f_, const float* __restrict__ z2f_,
                                              const float* __restrict__ hw1, const float* __restrict__ hb1,
                                              const float* __restrict__ hw2, const float* __restrict__ hb2,
                                              const float* __restrict__ lin_w, const float* __restrict__ lin_b,
                                              const float* __restrict__ lout_w, const float* __restrict__ lout_b,
                                              const float* __restrict__ loss_sum, float* __restrict__ out) {
    const int tid = threadIdx.x;
    const int b = blockIdx.x;
    __shared__ float z1s[32], z2s[32], oc[32], w[256], t1[16], t2[16];
    if (tid < 32) {
        oc[tid]  = x1[b * 32 + tid];
        z1s[tid] = z1f_[b * 32 + tid];
        z2s[tid] = z2f_[b * 32 + tid];
    }
    __syncthreads();
    for (int i = 0; i < LL; i++) {
        for (int p = tid; p < 256; p += 64) {
            float a = hb1[i * 256 + p], c = hb2[i * 256 + p];
#pragma unroll
            for (int d = 0; d < 32; d++) {
                a = fmaf(z1s[d], hw1[i * 8192 + d * 256 + p], a);
                c = fmaf(z2s[d], hw2[i * 8192 + d * 256 + p], c);
            }
            a = fminf(fmaxf(a, -NORMC), NORMC);  // clip(iw) + cw
            w[p] = a + c;
        }
        __syncthreads();
        if (tid < 16) {
            float s = lin_b[i * 16 + tid];
#pragma unroll
            for (int u = 0; u < 32; u++) s = fmaf(oc[u], lin_w[i * 512 + u * 16 + tid], s);
            t1[tid] = s;
        }
        __syncthreads();
        if (tid < 16) {
            float s = 0.f;
#pragma unroll
            for (int k2 = 0; k2 < 16; k2++) s = fmaf(t1[k2], w[k2 * 16 + tid], s);
            t2[tid] = s;
        }
        __syncthreads();
        if (tid < 32) {
            float s = lout_b[i * 32 + tid];
#pragma unroll
            for (int k2 = 0; k2 < 16; k2++) s = fmaf(t2[k2], lout_w[i * 512 + k2 * 32 + tid], s);
            oc[tid] = s;
        }
        __syncthreads();
    }
    if (tid < 32) out[(size_t)b * 32 + tid] = oc[tid];
    if (b == 0 && tid == 0) out[B * UU] = loss_sum[0] * (1.0f / (float)(B * S * D));
}

extern "C" void kernel_launch(void* const* d_in, const int* in_sizes, int n_in,
                              void* d_out, int out_size, void* d_ws, size_t ws_size,
                              hipStream_t stream) {
    const float* x1     = (const float*)d_in[0];
    const float* z1     = (const float*)d_in[1];
    const float* z2     = (const float*)d_in[3];
    const float* embd   = (const float*)d_in[4];
    const float* dec_w1 = (const float*)d_in[5];
    const float* dec_b1 = (const float*)d_in[6];
    const float* dec_w2 = (const float*)d_in[7];
    const float* dec_b2 = (const float*)d_in[8];
    const float* i_wih  = (const float*)d_in[9];
    const float* i_whh  = (const float*)d_in[10];
    const float* i_bih  = (const float*)d_in[11];
    const float* i_bhh  = (const float*)d_in[12];
    const float* c_wih  = (const float*)d_in[13];
    const float* c_whh  = (const float*)d_in[14];
    const float* c_bih  = (const float*)d_in[15];
    const float* c_bhh  = (const float*)d_in[16];
    const float* im_w1  = (const float*)d_in[17];
    const float* im_b1  = (const float*)d_in[18];
    const float* im_w2  = (const float*)d_in[19];
    const float* im_b2  = (const float*)d_in[20];
    const float* cm_w1  = (const float*)d_in[21];
    const float* cm_b1  = (const float*)d_in[22];
    const float* cm_w2  = (const float*)d_in[23];
    const float* cm_b2  = (const float*)d_in[24];
    const float* hw1    = (const float*)d_in[25];
    const float* hb1    = (const float*)d_in[26];
    const float* hw2    = (const float*)d_in[27];
    const float* hb2    = (const float*)d_in[28];
    const float* lin_w  = (const float*)d_in[29];
    const float* lin_b  = (const float*)d_in[30];
    const float* lout_w = (const float*)d_in[31];
    const float* lout_b = (const float*)d_in[32];

    float* wsf      = (float*)d_ws;
    float* loss_sum = wsf;                    // 1
    float* tnorm    = wsf + 64;               // 10000
    float* pb_s     = wsf + 10112;            // 25600
    int*   pb_v     = (int*)(wsf + 35712);    // 25600
    float* z_recon  = wsf + 61312;            // 256*31*32 = 253952
    float* z1f      = wsf + 315264;           // 8192
    float* z2f      = wsf + 323456;           // 8192 (end 331648 floats ~1.3MB)

    hipMemsetAsync(loss_sum, 0, sizeof(float), stream);
    k_tnorm<<<(V + 255) / 256, 256, 0, stream>>>(embd, tnorm);
    k_vq<<<(NROWS / VQ_R) * 2, 256, 0, stream>>>(z1, embd, tnorm, pb_s, pb_v);
    k_gather<<<NROWS / 256, 256, 0, stream>>>(z2, embd, pb_s, pb_v, dec_w1, dec_b1,
                                              dec_w2, dec_b2, z_recon, loss_sum);
    k_gru<<<512, 128, 0, stream>>>(z_recon, z2, i_wih, i_whh, i_bih, i_bhh,
                                   c_wih, c_whh, c_bih, c_bhh,
                                   im_w1, im_b1, im_w2, im_b2,
                                   cm_w1, cm_b1, cm_w2, cm_b2, z1f, z2f);
    k_hyper<<<B, 64, 0, stream>>>(x1, z1f, z2f, hw1, hb1, hw2, hb2,
                                  lin_w, lin_b, lout_w, lout_b, loss_sum, (float*)d_out);
}

// Round 2
// 364.156 us; speedup vs baseline: 2.1067x; 2.1067x over previous
//
#include <hip/hip_runtime.h>
#include <math.h>

#define B 256
#define S 50
#define D 32
#define V 10000
#define VPAD 10240
#define KK 16
#define HH 64
#define LL 2
#define UU 32
#define TT 30          // trigger_seq_length
#define NROWS (B*S)    // 12800
#define NORMC 0.01f
#define CH 256         // codes per LDS chunk in k_vq
#define VHALF 5000

typedef __attribute__((ext_vector_type(8))) short bf16x8;
typedef __attribute__((ext_vector_type(4))) float f32x4;

__device__ __forceinline__ float sigmoidf_(float x) { return 1.0f / (1.0f + expf(-x)); }

__device__ __forceinline__ unsigned short f2bf(float x) {
    union { float f; unsigned int u; } a; a.f = x;
    unsigned int u = a.u;
    return (unsigned short)((u + 0x7FFFu + ((u >> 16) & 1u)) >> 16);  // RNE, inputs finite
}
__device__ __forceinline__ float bf2f(unsigned short h) {
    union { unsigned int u; float f; } a; a.u = ((unsigned int)h) << 16; return a.f;
}

__device__ __forceinline__ void gld16(void* lds, const void* g) {
    __builtin_amdgcn_global_load_lds(
        (const __attribute__((address_space(1))) unsigned int*)g,
        (__attribute__((address_space(3))) unsigned int*)lds, 16, 0, 0);
}
__device__ __forceinline__ void gld4(void* lds, const void* g) {
    __builtin_amdgcn_global_load_lds(
        (const __attribute__((address_space(1))) unsigned int*)g,
        (__attribute__((address_space(3))) unsigned int*)lds, 4, 0, 0);
}

// ---------------- prep: split fp32 -> (hi,lo) bf16 for embd and z1; tnorm; zero loss ----------------
// quarter-threads: gid<40000 -> code quarters; 40000..91199 -> row quarters
__global__ __launch_bounds__(256) void k_prep(const float* __restrict__ embd,
                                              const float* __restrict__ z1,
                                              unsigned short* __restrict__ Eh, unsigned short* __restrict__ El,
                                              unsigned short* __restrict__ Qh, unsigned short* __restrict__ Ql,
                                              float* __restrict__ tn, float* __restrict__ loss_sum) {
    int gid = blockIdx.x * 256 + threadIdx.x;
    if (gid == 0) loss_sum[0] = 0.f;
    if (gid >= 40000 + 4 * NROWS) return;
    const float* src;
    unsigned short *dh, *dl;
    int isRow = (gid >= 40000);
    int item, qd;
    if (!isRow) {
        item = gid >> 2; qd = gid & 3;
        src = embd + (size_t)item * D + qd * 8;
        dh = Eh + (size_t)item * D + qd * 8;
        dl = El + (size_t)item * D + qd * 8;
    } else {
        int g = gid - 40000;
        item = g >> 2; qd = g & 3;
        src = z1 + (size_t)item * D + qd * 8;
        dh = Qh + (size_t)item * D + qd * 8;
        dl = Ql + (size_t)item * D + qd * 8;
    }
    float4 x0 = *(const float4*)(src);
    float4 x1 = *(const float4*)(src + 4);
    float xs[8] = {x0.x, x0.y, x0.z, x0.w, x1.x, x1.y, x1.z, x1.w};
    unsigned short hv[8], lv[8];
    float ss = 0.f;
#pragma unroll
    for (int i = 0; i < 8; i++) {
        float x = xs[i];
        ss = fmaf(x, x, ss);
        unsigned short h = f2bf(x);
        hv[i] = h;
        lv[i] = f2bf(x - bf2f(h));
    }
    *(uint4*)dh = *(const uint4*)hv;
    *(uint4*)dl = *(const uint4*)lv;
    if (!isRow) {
        ss += __shfl_xor(ss, 1);
        ss += __shfl_xor(ss, 2);
        if (qd == 0) tn[item] = 0.5f * ss;
    }
}

// ---------------- VQ argmin via split-bf16 MFMA ----------------
// Block: 256 thr = 4 waves; 32 rows x half of V. wave: rowtile=w&1, col-group=w>>1.
// Per chunk: 256 codes staged to LDS via global_load_lds; per col-tile: 4 chained MFMA.
__global__ __launch_bounds__(256) void k_vq(const short* __restrict__ Qh, const short* __restrict__ Ql,
                                            const short* __restrict__ Eh, const short* __restrict__ El,
                                            const float* __restrict__ tn,
                                            float* __restrict__ pb_s, int* __restrict__ pb_v) {
    __shared__ __attribute__((aligned(16))) short EhL[CH * 32];  // 16 KB, 64B/code rows
    __shared__ __attribute__((aligned(16))) short ElL[CH * 32];  // 16 KB
    __shared__ float tnL[CH];
    __shared__ float redS[2][32];
    __shared__ int   redV[2][32];
    const int tid = threadIdx.x;
    const int wave = tid >> 6, lane = tid & 63;
    const int rb = blockIdx.x >> 1, half = blockIdx.x & 1;
    const int row0 = rb * 32;
    const int rowtile = wave & 1, grp = wave >> 1;
    const int quad = lane >> 4, c15 = lane & 15;
    // A fragments (fixed all kernel): A[m=lane&15][k=quad*8+j]
    const int arow = row0 + rowtile * 16 + c15;
    bf16x8 ah = *(const bf16x8*)(Qh + (size_t)arow * 32 + quad * 8);
    bf16x8 al = *(const bf16x8*)(Ql + (size_t)arow * 32 + quad * 8);
    float best[4]; int bestv[4];
#pragma unroll
    for (int i = 0; i < 4; i++) { best[i] = INFINITY; bestv[i] = 0x7fffffff; }
    const int vbeg = half * VHALF;
    for (int c0 = 0; c0 < VHALF; c0 += CH) {
        __syncthreads();  // previous chunk fully consumed
        {   // stage 256 codes: Eh/El 16KB each + tn 1KB; per wave: 4+4+1 issues
            const size_t sb = (size_t)(vbeg + c0) * 32;
            const int wo = wave * 2048;  // shorts
#pragma unroll
            for (int i = 0; i < 4; i++) {
                gld16(EhL + wo + i * 512, Eh + sb + wo + i * 512 + lane * 8);
                gld16(ElL + wo + i * 512, El + sb + wo + i * 512 + lane * 8);
            }
            gld4(tnL + wave * 64, tn + (vbeg + c0) + wave * 64 + lane);
        }
        __syncthreads();  // vmcnt(0) drain -> staged data visible
#pragma unroll
        for (int t8 = 0; t8 < 8; t8++) {
            const int t = grp * 8 + t8;
            const int code = t * 16 + c15;
            bf16x8 bh = *(const bf16x8*)(EhL + code * 32 + quad * 8);
            bf16x8 bl = *(const bf16x8*)(ElL + code * 32 + quad * 8);
            f32x4 acc = {0.f, 0.f, 0.f, 0.f};
            acc = __builtin_amdgcn_mfma_f32_16x16x32_bf16(ah, bh, acc, 0, 0, 0);
            acc = __builtin_amdgcn_mfma_f32_16x16x32_bf16(al, bh, acc, 0, 0, 0);
            acc = __builtin_amdgcn_mfma_f32_16x16x32_bf16(ah, bl, acc, 0, 0, 0);
            acc = __builtin_amdgcn_mfma_f32_16x16x32_bf16(al, bl, acc, 0, 0, 0);
            const int v = vbeg + c0 + code;
            const float tnv = tnL[code];
            if (v < V) {
#pragma unroll
                for (int i = 0; i < 4; i++) {
                    float s = tnv - acc[i];  // 0.5*||t||^2 - q.t
                    if (s < best[i]) { best[i] = s; bestv[i] = v; }
                }
            }
        }
    }
    // reduce across the 16 col-lanes (lane bits 0..3); rows live at quad*4+i
#pragma unroll
    for (int m = 1; m <= 8; m <<= 1) {
#pragma unroll
        for (int i = 0; i < 4; i++) {
            float os = __shfl_xor(best[i], m);
            int   ov = __shfl_xor(bestv[i], m);
            if (os < best[i] || (os == best[i] && ov < bestv[i])) { best[i] = os; bestv[i] = ov; }
        }
    }
    if (c15 == 0) {
#pragma unroll
        for (int i = 0; i < 4; i++) {
            redS[grp][rowtile * 16 + quad * 4 + i] = best[i];
            redV[grp][rowtile * 16 + quad * 4 + i] = bestv[i];
        }
    }
    __syncthreads();
    if (tid < 32) {
        float s0 = redS[0][tid]; int v0 = redV[0][tid];
        float s1 = redS[1][tid]; int v1 = redV[1][tid];
        bool t1 = (s1 < s0) || (s1 == s0 && v1 < v0);
        pb_s[(size_t)(row0 + tid) * 2 + half] = t1 ? s1 : s0;
        pb_v[(size_t)(row0 + tid) * 2 + half] = t1 ? v1 : v0;
    }
}

// ---------------- gather z_emb, VQ loss, decoder (s<=TT only) ----------------
__global__ __launch_bounds__(256) void k_gather(const float* __restrict__ z2,
                                                const float* __restrict__ embd,
                                                const float* __restrict__ pb_s,
                                                const int* __restrict__ pb_v,
                                                const float* __restrict__ dw1,
                                                const float* __restrict__ db1,
                                                const float* __restrict__ dw2,
                                                const float* __restrict__ db2,
                                                float* __restrict__ z_recon,
                                                float* __restrict__ loss_sum) {
    int row = blockIdx.x * 256 + threadIdx.x;  // 0..12799
    float s0 = pb_s[row * 2], s1 = pb_s[row * 2 + 1];
    int v0 = pb_v[row * 2], v1 = pb_v[row * 2 + 1];
    int vid = (s1 < s0 || (s1 == s0 && v1 < v0)) ? v1 : v0;
    const float* ze = embd + (size_t)vid * D;
    float zer[32];
#pragma unroll
    for (int j = 0; j < 8; j++) {
        float4 e4 = *(const float4*)(ze + 4 * j);
        zer[4 * j] = e4.x; zer[4 * j + 1] = e4.y; zer[4 * j + 2] = e4.z; zer[4 * j + 3] = e4.w;
    }
    float ls = 0.f;
#pragma unroll
    for (int j = 0; j < 8; j++) {
        float4 x4 = *(const float4*)(z2 + (size_t)row * D + 4 * j);
        float d0 = x4.x - zer[4 * j], d1 = x4.y - zer[4 * j + 1];
        float d2 = x4.z - zer[4 * j + 2], d3 = x4.w - zer[4 * j + 3];
        ls += d0 * d0 + d1 * d1 + d2 * d2 + d3 * d3;
    }
#pragma unroll
    for (int off = 32; off > 0; off >>= 1) ls += __shfl_down(ls, off);
    if ((threadIdx.x & 63) == 0) atomicAdd(loss_sum, ls);
    int s = row % S;
    if (s <= TT) {
        int b = row / S;
        float zr[32];
#pragma unroll
        for (int d = 0; d < 32; d++) zr[d] = db2[d];
        for (int h = 0; h < 64; h++) {
            float a = db1[h];
#pragma unroll
            for (int d = 0; d < 32; d++) a = fmaf(zer[d], dw1[d * 64 + h], a);
            a = (a >= 0.f) ? a : 0.1f * a;  // leaky_relu 0.1
#pragma unroll
            for (int d = 0; d < 32; d++) zr[d] = fmaf(a, dw2[h * 32 + d], zr[d]);
        }
        float* outp = z_recon + (size_t)b * ((TT + 1) * D) + s * D;
#pragma unroll
        for (int d = 0; d < 32; d++) outp[d] = zr[d];
    }
}

// ---------------- GRU (31 steps) + output MLP; 512 blocks: [gru][sample] ----------------
__global__ __launch_bounds__(128) void k_gru(const float* __restrict__ z_recon,
                                             const float* __restrict__ z2,
                                             const float* __restrict__ i_wih, const float* __restrict__ i_whh,
                                             const float* __restrict__ i_bih, const float* __restrict__ i_bhh,
                                             const float* __restrict__ c_wih, const float* __restrict__ c_whh,
                                             const float* __restrict__ c_bih, const float* __restrict__ c_bhh,
                                             const float* __restrict__ im_w1, const float* __restrict__ im_b1,
                                             const float* __restrict__ im_w2, const float* __restrict__ im_b2,
                                             const float* __restrict__ cm_w1, const float* __restrict__ cm_b1,
                                             const float* __restrict__ cm_w2, const float* __restrict__ cm_b2,
                                             float* __restrict__ z1f, float* __restrict__ z2f) {
    const int tid = threadIdx.x;
    const int which = blockIdx.x >> 8;
    const int b = blockIdx.x & 255;
    const float* x; int xstride;
    const float *wih, *whh, *bih, *bhh, *w1, *b1, *w2, *b2; float* zf;
    if (which == 0) { x = z_recon; xstride = (TT + 1) * D; wih = i_wih; whh = i_whh; bih = i_bih; bhh = i_bhh; w1 = im_w1; b1 = im_b1; w2 = im_w2; b2 = im_b2; zf = z1f; }
    else            { x = z2;      xstride = S * D;        wih = c_wih; whh = c_whh; bih = c_bih; bhh = c_bhh; w1 = cm_w1; b1 = cm_b1; w2 = cm_w2; b2 = cm_b2; zf = z2f; }
    __shared__ float wihT[32][97];  // [d][e] pad 97 -> conflict-free
    __shared__ float whhT[32][97];
    __shared__ float gi[TT + 1][96];
    __shared__ float xs[TT + 1][32];
    __shared__ float hsh[32];
    __shared__ float gh[96];
    __shared__ float bh2[96];
    __shared__ float af[32];
    for (int p = tid; p < 96 * 32; p += 128) {
        int e = p >> 5, d = p & 31;
        wihT[d][e] = wih[p];
        whhT[d][e] = whh[p];
    }
    for (int p = tid; p < (TT + 1) * D; p += 128) xs[p >> 5][p & 31] = x[(size_t)b * xstride + p];
    if (tid < 96) bh2[tid] = bhh[tid];
    if (tid < 32) hsh[tid] = 0.f;
    __syncthreads();
    for (int p = tid; p < (TT + 1) * 96; p += 128) {
        int s = p / 96, e = p % 96;
        float g = bih[e];
#pragma unroll
        for (int d = 0; d < 32; d++) g = fmaf(xs[s][d], wihT[d][e], g);
        gi[s][e] = g;
    }
    __syncthreads();
    for (int t = 0; t <= TT; t++) {
        if (tid < 96) {
            float g = bh2[tid];
#pragma unroll
            for (int d = 0; d < 32; d++) g = fmaf(hsh[d], whhT[d][tid], g);
            gh[tid] = g;
        }
        __syncthreads();
        float hn = 0.f;
        if (tid < 32) {
            float rr = sigmoidf_(gi[t][tid] + gh[tid]);
            float zz = sigmoidf_(gi[t][tid + 32] + gh[tid + 32]);
            float nn = tanhf(gi[t][tid + 64] + rr * gh[tid + 64]);
            hn = (1.f - zz) * nn + zz * hsh[tid];
        }
        __syncthreads();
        if (tid < 32) hsh[tid] = hn;
        __syncthreads();
    }
    if (tid < 32) {
        float a = b1[tid];
#pragma unroll
        for (int d = 0; d < 32; d++) a = fmaf(hsh[d], w1[d * 32 + tid], a);
        af[tid] = tanhf(a);
    }
    __syncthreads();
    if (tid < 32) {
        float o = b2[tid];
#pragma unroll
        for (int d = 0; d < 32; d++) o = fmaf(af[d], w2[d * 32 + tid], o);
        zf[(size_t)b * 32 + tid] = o;
    }
}

// ---------------- hypernetwork epilogue + loss write ----------------
__global__ __launch_bounds__(64) void k_hyper(const float* __restrict__ x1,
                                              const float* __restrict__ z1f_, const float* __restrict__ z2f_,
                                              const float* __restrict__ hw1, const float* __restrict__ hb1,
                                              const float* __restrict__ hw2, const float* __restrict__ hb2,
                                              const float* __restrict__ lin_w, const float* __restrict__ lin_b,
                                              const float* __restrict__ lout_w, const float* __restrict__ lout_b,
                                              const float* __restrict__ loss_sum, float* __restrict__ out) {
    const int tid = threadIdx.x;
    const int b = blockIdx.x;
    __shared__ float z1s[32], z2s[32], oc[32], w[256], t1[16], t2[16];
    if (tid < 32) {
        oc[tid]  = x1[b * 32 + tid];
        z1s[tid] = z1f_[b * 32 + tid];
        z2s[tid] = z2f_[b * 32 + tid];
    }
    __syncthreads();
    for (int i = 0; i < LL; i++) {
        for (int p = tid; p < 256; p += 64) {
            float a = hb1[i * 256 + p], c = hb2[i * 256 + p];
#pragma unroll
            for (int d = 0; d < 32; d++) {
                a = fmaf(z1s[d], hw1[i * 8192 + d * 256 + p], a);
                c = fmaf(z2s[d], hw2[i * 8192 + d * 256 + p], c);
            }
            a = fminf(fmaxf(a, -NORMC), NORMC);  // clip(iw) + cw
            w[p] = a + c;
        }
        __syncthreads();
        if (tid < 16) {
            float s = lin_b[i * 16 + tid];
#pragma unroll
            for (int u = 0; u < 32; u++) s = fmaf(oc[u], lin_w[i * 512 + u * 16 + tid], s);
            t1[tid] = s;
        }
        __syncthreads();
        if (tid < 16) {
            float s = 0.f;
#pragma unroll
            for (int k2 = 0; k2 < 16; k2++) s = fmaf(t1[k2], w[k2 * 16 + tid], s);
            t2[tid] = s;
        }
        __syncthreads();
        if (tid < 32) {
            float s = lout_b[i * 32 + tid];
#pragma unroll
            for (int k2 = 0; k2 < 16; k2++) s = fmaf(t2[k2], lout_w[i * 512 + k2 * 32 + tid], s);
            oc[tid] = s;
        }
        __syncthreads();
    }
    if (tid < 32) out[(size_t)b * 32 + tid] = oc[tid];
    if (b == 0 && tid == 0) out[B * UU] = loss_sum[0] * (1.0f / (float)(B * S * D));
}

extern "C" void kernel_launch(void* const* d_in, const int* in_sizes, int n_in,
                              void* d_out, int out_size, void* d_ws, size_t ws_size,
                              hipStream_t stream) {
    const float* x1     = (const float*)d_in[0];
    const float* z1     = (const float*)d_in[1];
    const float* z2     = (const float*)d_in[3];
    const float* embd   = (const float*)d_in[4];
    const float* dec_w1 = (const float*)d_in[5];
    const float* dec_b1 = (const float*)d_in[6];
    const float* dec_w2 = (const float*)d_in[7];
    const float* dec_b2 = (const float*)d_in[8];
    const float* i_wih  = (const float*)d_in[9];
    const float* i_whh  = (const float*)d_in[10];
    const float* i_bih  = (const float*)d_in[11];
    const float* i_bhh  = (const float*)d_in[12];
    const float* c_wih  = (const float*)d_in[13];
    const float* c_whh  = (const float*)d_in[14];
    const float* c_bih  = (const float*)d_in[15];
    const float* c_bhh  = (const float*)d_in[16];
    const float* im_w1  = (const float*)d_in[17];
    const float* im_b1  = (const float*)d_in[18];
    const float* im_w2  = (const float*)d_in[19];
    const float* im_b2  = (const float*)d_in[20];
    const float* cm_w1  = (const float*)d_in[21];
    const float* cm_b1  = (const float*)d_in[22];
    const float* cm_w2  = (const float*)d_in[23];
    const float* cm_b2  = (const float*)d_in[24];
    const float* hw1    = (const float*)d_in[25];
    const float* hb1    = (const float*)d_in[26];
    const float* hw2    = (const float*)d_in[27];
    const float* hb2    = (const float*)d_in[28];
    const float* lin_w  = (const float*)d_in[29];
    const float* lin_b  = (const float*)d_in[30];
    const float* lout_w = (const float*)d_in[31];
    const float* lout_b = (const float*)d_in[32];

    // workspace layout (floats)
    float* wsf      = (float*)d_ws;
    float* loss_sum = wsf;                       // 1 (pad to 64)
    float* tn       = wsf + 64;                  // VPAD = 10240
    float* pb_s     = wsf + 10304;               // 25600
    int*   pb_v     = (int*)(wsf + 35904);       // 25600
    float* z_recon  = wsf + 61504;               // 256*31*32 = 253952
    float* z1f      = wsf + 315456;              // 8192
    float* z2f      = wsf + 323648;              // 8192 -> 331840
    unsigned short* Eh = (unsigned short*)(wsf + 331840);  // VPAD*32 bf16 = 163840 f
    unsigned short* El = (unsigned short*)(wsf + 495680);  // 163840 f
    unsigned short* Qh = (unsigned short*)(wsf + 659520);  // NROWS*32 bf16 = 204800 f
    unsigned short* Ql = (unsigned short*)(wsf + 864320);  // 204800 f -> end 1069120 f (~4.3 MB)

    k_prep<<<(40000 + 4 * NROWS + 255) / 256, 256, 0, stream>>>(embd, z1, Eh, El, Qh, Ql, tn, loss_sum);
    k_vq<<<(NROWS / 32) * 2, 256, 0, stream>>>((const short*)Qh, (const short*)Ql,
                                               (const short*)Eh, (const short*)El, tn, pb_s, pb_v);
    k_gather<<<NROWS / 256, 256, 0, stream>>>(z2, embd, pb_s, pb_v, dec_w1, dec_b1,
                                              dec_w2, dec_b2, z_recon, loss_sum);
    k_gru<<<512, 128, 0, stream>>>(z_recon, z2, i_wih, i_whh, i_bih, i_bhh,
                                   c_wih, c_whh, c_bih, c_bhh,
                                   im_w1, im_b1, im_w2, im_b2,
                                   cm_w1, cm_b1, cm_w2, cm_b2, z1f, z2f);
    k_hyper<<<B, 64, 0, stream>>>(x1, z1f, z2f, hw1, hb1, hw2, hb2,
                                  lin_w, lin_b, lout_w, lout_b, loss_sum, (float*)d_out);
}

// Round 3
// 253.074 us; speedup vs baseline: 3.0314x; 1.4389x over previous
//
#include <hip/hip_runtime.h>
#include <math.h>

#define B 256
#define S 50
#define D 32
#define V 10000
#define VPAD 10240
#define KK 16
#define HH 64
#define LL 2
#define UU 32
#define TT 30          // trigger_seq_length
#define NROWS (B*S)    // 12800
#define NORMC 0.01f
#define CH 256         // codes per LDS chunk in k_vq
#define VHALF 5000

typedef __attribute__((ext_vector_type(8))) short bf16x8;
typedef __attribute__((ext_vector_type(4))) float f32x4;

__device__ __forceinline__ float sigmoidf_(float x) { return 1.0f / (1.0f + expf(-x)); }

__device__ __forceinline__ unsigned short f2bf(float x) {
    union { float f; unsigned int u; } a; a.f = x;
    unsigned int u = a.u;
    return (unsigned short)((u + 0x7FFFu + ((u >> 16) & 1u)) >> 16);  // RNE, inputs finite
}
__device__ __forceinline__ float bf2f(unsigned short h) {
    union { unsigned int u; float f; } a; a.u = ((unsigned int)h) << 16; return a.f;
}

__device__ __forceinline__ void gld16(void* lds, const void* g) {
    __builtin_amdgcn_global_load_lds(
        (const __attribute__((address_space(1))) unsigned int*)g,
        (__attribute__((address_space(3))) unsigned int*)lds, 16, 0, 0);
}
__device__ __forceinline__ void gld4(void* lds, const void* g) {
    __builtin_amdgcn_global_load_lds(
        (const __attribute__((address_space(1))) unsigned int*)g,
        (__attribute__((address_space(3))) unsigned int*)lds, 4, 0, 0);
}

// ---------------- prep: split fp32 -> (hi,lo) bf16 for embd and z1; tnorm; zero loss ----------------
__global__ __launch_bounds__(256) void k_prep(const float* __restrict__ embd,
                                              const float* __restrict__ z1,
                                              unsigned short* __restrict__ Eh, unsigned short* __restrict__ El,
                                              unsigned short* __restrict__ Qh, unsigned short* __restrict__ Ql,
                                              float* __restrict__ tn, float* __restrict__ loss_sum) {
    int gid = blockIdx.x * 256 + threadIdx.x;
    if (gid == 0) loss_sum[0] = 0.f;
    if (gid >= 40000 + 4 * NROWS) return;
    const float* src;
    unsigned short *dh, *dl;
    int isRow = (gid >= 40000);
    int item, qd;
    if (!isRow) {
        item = gid >> 2; qd = gid & 3;
        src = embd + (size_t)item * D + qd * 8;
        dh = Eh + (size_t)item * D + qd * 8;
        dl = El + (size_t)item * D + qd * 8;
    } else {
        int g = gid - 40000;
        item = g >> 2; qd = g & 3;
        src = z1 + (size_t)item * D + qd * 8;
        dh = Qh + (size_t)item * D + qd * 8;
        dl = Ql + (size_t)item * D + qd * 8;
    }
    float4 x0 = *(const float4*)(src);
    float4 x1 = *(const float4*)(src + 4);
    float xs[8] = {x0.x, x0.y, x0.z, x0.w, x1.x, x1.y, x1.z, x1.w};
    unsigned short hv[8], lv[8];
    float ss = 0.f;
#pragma unroll
    for (int i = 0; i < 8; i++) {
        float x = xs[i];
        ss = fmaf(x, x, ss);
        unsigned short h = f2bf(x);
        hv[i] = h;
        lv[i] = f2bf(x - bf2f(h));
    }
    *(uint4*)dh = *(const uint4*)hv;
    *(uint4*)dl = *(const uint4*)lv;
    if (!isRow) {
        ss += __shfl_xor(ss, 1);
        ss += __shfl_xor(ss, 2);
        if (qd == 0) tn[item] = 0.5f * ss;
    }
}

// ---------------- VQ argmin via split-bf16 MFMA ----------------
__global__ __launch_bounds__(256) void k_vq(const short* __restrict__ Qh, const short* __restrict__ Ql,
                                            const short* __restrict__ Eh, const short* __restrict__ El,
                                            const float* __restrict__ tn,
                                            float* __restrict__ pb_s, int* __restrict__ pb_v) {
    __shared__ __attribute__((aligned(16))) short EhL[CH * 32];  // 16 KB
    __shared__ __attribute__((aligned(16))) short ElL[CH * 32];  // 16 KB
    __shared__ float tnL[CH];
    __shared__ float redS[2][32];
    __shared__ int   redV[2][32];
    const int tid = threadIdx.x;
    const int wave = tid >> 6, lane = tid & 63;
    const int rb = blockIdx.x >> 1, half = blockIdx.x & 1;
    const int row0 = rb * 32;
    const int rowtile = wave & 1, grp = wave >> 1;
    const int quad = lane >> 4, c15 = lane & 15;
    const int arow = row0 + rowtile * 16 + c15;
    bf16x8 ah = *(const bf16x8*)(Qh + (size_t)arow * 32 + quad * 8);
    bf16x8 al = *(const bf16x8*)(Ql + (size_t)arow * 32 + quad * 8);
    float best[4]; int bestv[4];
#pragma unroll
    for (int i = 0; i < 4; i++) { best[i] = INFINITY; bestv[i] = 0x7fffffff; }
    const int vbeg = half * VHALF;
    for (int c0 = 0; c0 < VHALF; c0 += CH) {
        __syncthreads();
        {
            const size_t sb = (size_t)(vbeg + c0) * 32;
            const int wo = wave * 2048;
#pragma unroll
            for (int i = 0; i < 4; i++) {
                gld16(EhL + wo + i * 512, Eh + sb + wo + i * 512 + lane * 8);
                gld16(ElL + wo + i * 512, El + sb + wo + i * 512 + lane * 8);
            }
            gld4(tnL + wave * 64, tn + (vbeg + c0) + wave * 64 + lane);
        }
        __syncthreads();
#pragma unroll
        for (int t8 = 0; t8 < 8; t8++) {
            const int t = grp * 8 + t8;
            const int code = t * 16 + c15;
            bf16x8 bh = *(const bf16x8*)(EhL + code * 32 + quad * 8);
            bf16x8 bl = *(const bf16x8*)(ElL + code * 32 + quad * 8);
            f32x4 acc = {0.f, 0.f, 0.f, 0.f};
            acc = __builtin_amdgcn_mfma_f32_16x16x32_bf16(ah, bh, acc, 0, 0, 0);
            acc = __builtin_amdgcn_mfma_f32_16x16x32_bf16(al, bh, acc, 0, 0, 0);
            acc = __builtin_amdgcn_mfma_f32_16x16x32_bf16(ah, bl, acc, 0, 0, 0);
            acc = __builtin_amdgcn_mfma_f32_16x16x32_bf16(al, bl, acc, 0, 0, 0);
            const int v = vbeg + c0 + code;
            const float tnv = tnL[code];
            if (v < V) {
#pragma unroll
                for (int i = 0; i < 4; i++) {
                    float s = tnv - acc[i];
                    if (s < best[i]) { best[i] = s; bestv[i] = v; }
                }
            }
        }
    }
#pragma unroll
    for (int m = 1; m <= 8; m <<= 1) {
#pragma unroll
        for (int i = 0; i < 4; i++) {
            float os = __shfl_xor(best[i], m);
            int   ov = __shfl_xor(bestv[i], m);
            if (os < best[i] || (os == best[i] && ov < bestv[i])) { best[i] = os; bestv[i] = ov; }
        }
    }
    if (c15 == 0) {
#pragma unroll
        for (int i = 0; i < 4; i++) {
            redS[grp][rowtile * 16 + quad * 4 + i] = best[i];
            redV[grp][rowtile * 16 + quad * 4 + i] = bestv[i];
        }
    }
    __syncthreads();
    if (tid < 32) {
        float s0 = redS[0][tid]; int v0 = redV[0][tid];
        float s1 = redS[1][tid]; int v1 = redV[1][tid];
        bool t1 = (s1 < s0) || (s1 == s0 && v1 < v0);
        pb_s[(size_t)(row0 + tid) * 2 + half] = t1 ? s1 : s0;
        pb_v[(size_t)(row0 + tid) * 2 + half] = t1 ? v1 : v0;
    }
}

// ---------------- gather z_emb, VQ loss, decoder (s<=TT only) ----------------
__global__ __launch_bounds__(256) void k_gather(const float* __restrict__ z2,
                                                const float* __restrict__ embd,
                                                const float* __restrict__ pb_s,
                                                const int* __restrict__ pb_v,
                                                const float* __restrict__ dw1,
                                                const float* __restrict__ db1,
                                                const float* __restrict__ dw2,
                                                const float* __restrict__ db2,
                                                float* __restrict__ z_recon,
                                                float* __restrict__ loss_sum) {
    int row = blockIdx.x * 256 + threadIdx.x;  // 0..12799
    float s0 = pb_s[row * 2], s1 = pb_s[row * 2 + 1];
    int v0 = pb_v[row * 2], v1 = pb_v[row * 2 + 1];
    int vid = (s1 < s0 || (s1 == s0 && v1 < v0)) ? v1 : v0;
    const float* ze = embd + (size_t)vid * D;
    float zer[32];
#pragma unroll
    for (int j = 0; j < 8; j++) {
        float4 e4 = *(const float4*)(ze + 4 * j);
        zer[4 * j] = e4.x; zer[4 * j + 1] = e4.y; zer[4 * j + 2] = e4.z; zer[4 * j + 3] = e4.w;
    }
    float ls = 0.f;
#pragma unroll
    for (int j = 0; j < 8; j++) {
        float4 x4 = *(const float4*)(z2 + (size_t)row * D + 4 * j);
        float d0 = x4.x - zer[4 * j], d1 = x4.y - zer[4 * j + 1];
        float d2 = x4.z - zer[4 * j + 2], d3 = x4.w - zer[4 * j + 3];
        ls += d0 * d0 + d1 * d1 + d2 * d2 + d3 * d3;
    }
#pragma unroll
    for (int off = 32; off > 0; off >>= 1) ls += __shfl_down(ls, off);
    if ((threadIdx.x & 63) == 0) atomicAdd(loss_sum, ls);
    int s = row % S;
    if (s <= TT) {
        int b = row / S;
        float zr[32];
#pragma unroll
        for (int d = 0; d < 32; d++) zr[d] = db2[d];
        for (int h = 0; h < 64; h++) {
            float a = db1[h];
#pragma unroll
            for (int d = 0; d < 32; d++) a = fmaf(zer[d], dw1[d * 64 + h], a);
            a = (a >= 0.f) ? a : 0.1f * a;  // leaky_relu 0.1
#pragma unroll
            for (int d = 0; d < 32; d++) zr[d] = fmaf(a, dw2[h * 32 + d], zr[d]);
        }
        float* outp = z_recon + (size_t)b * ((TT + 1) * D) + s * D;
#pragma unroll
        for (int d = 0; d < 32; d++) outp[d] = zr[d];
    }
}

// ---------------- GRU (31 steps) + output MLP; 512 blocks: [gru][sample] ----------------
__global__ __launch_bounds__(128) void k_gru(const float* __restrict__ z_recon,
                                             const float* __restrict__ z2,
                                             const float* __restrict__ i_wih, const float* __restrict__ i_whh,
                                             const float* __restrict__ i_bih, const float* __restrict__ i_bhh,
                                             const float* __restrict__ c_wih, const float* __restrict__ c_whh,
                                             const float* __restrict__ c_bih, const float* __restrict__ c_bhh,
                                             const float* __restrict__ im_w1, const float* __restrict__ im_b1,
                                             const float* __restrict__ im_w2, const float* __restrict__ im_b2,
                                             const float* __restrict__ cm_w1, const float* __restrict__ cm_b1,
                                             const float* __restrict__ cm_w2, const float* __restrict__ cm_b2,
                                             float* __restrict__ z1f, float* __restrict__ z2f) {
    const int tid = threadIdx.x;
    const int which = blockIdx.x >> 8;
    const int b = blockIdx.x & 255;
    const float* x; int xstride;
    const float *wih, *whh, *bih, *bhh, *w1, *b1, *w2, *b2; float* zf;
    if (which == 0) { x = z_recon; xstride = (TT + 1) * D; wih = i_wih; whh = i_whh; bih = i_bih; bhh = i_bhh; w1 = im_w1; b1 = im_b1; w2 = im_w2; b2 = im_b2; zf = z1f; }
    else            { x = z2;      xstride = S * D;        wih = c_wih; whh = c_whh; bih = c_bih; bhh = c_bhh; w1 = cm_w1; b1 = cm_b1; w2 = cm_w2; b2 = cm_b2; zf = z2f; }
    __shared__ float wihT[32][97];
    __shared__ float whhT[32][97];
    __shared__ float gi[TT + 1][96];
    __shared__ float xs[TT + 1][32];
    __shared__ float hsh[32];
    __shared__ float gh[96];
    __shared__ float bh2[96];
    __shared__ float af[32];
    for (int p = tid; p < 96 * 32; p += 128) {
        int e = p >> 5, d = p & 31;
        wihT[d][e] = wih[p];
        whhT[d][e] = whh[p];
    }
    for (int p = tid; p < (TT + 1) * D; p += 128) xs[p >> 5][p & 31] = x[(size_t)b * xstride + p];
    if (tid < 96) bh2[tid] = bhh[tid];
    if (tid < 32) hsh[tid] = 0.f;
    __syncthreads();
    for (int p = tid; p < (TT + 1) * 96; p += 128) {
        int s = p / 96, e = p % 96;
        float g = bih[e];
#pragma unroll
        for (int d = 0; d < 32; d++) g = fmaf(xs[s][d], wihT[d][e], g);
        gi[s][e] = g;
    }
    __syncthreads();
    for (int t = 0; t <= TT; t++) {
        if (tid < 96) {
            float g = bh2[tid];
#pragma unroll
            for (int d = 0; d < 32; d++) g = fmaf(hsh[d], whhT[d][tid], g);
            gh[tid] = g;
        }
        __syncthreads();
        float hn = 0.f;
        if (tid < 32) {
            float rr = sigmoidf_(gi[t][tid] + gh[tid]);
            float zz = sigmoidf_(gi[t][tid + 32] + gh[tid + 32]);
            float nn = tanhf(gi[t][tid + 64] + rr * gh[tid + 64]);
            hn = (1.f - zz) * nn + zz * hsh[tid];
        }
        __syncthreads();
        if (tid < 32) hsh[tid] = hn;
        __syncthreads();
    }
    if (tid < 32) {
        float a = b1[tid];
#pragma unroll
        for (int d = 0; d < 32; d++) a = fmaf(hsh[d], w1[d * 32 + tid], a);
        af[tid] = tanhf(a);
    }
    __syncthreads();
    if (tid < 32) {
        float o = b2[tid];
#pragma unroll
        for (int d = 0; d < 32; d++) o = fmaf(af[d], w2[d * 32 + tid], o);
        zf[(size_t)b * 32 + tid] = o;
    }
}

// ---------------- hypernet weight-gen: w[b][p] = clip(z1f.hw1) + z2f.hw2 ----------------
// 512 blocks x 256 thr: block (2b + parity) covers sample b, layer = parity, 256 kk each.
__global__ __launch_bounds__(256) void k_wgen(const float* __restrict__ z1f_, const float* __restrict__ z2f_,
                                              const float* __restrict__ hw1, const float* __restrict__ hb1,
                                              const float* __restrict__ hw2, const float* __restrict__ hb2,
                                              float* __restrict__ w_out) {
    __shared__ float z1s[32], z2s[32];
    const int tid = threadIdx.x;
    const int b = blockIdx.x >> 1;
    const int layer = blockIdx.x & 1;
    if (tid < 32) z1s[tid] = z1f_[b * 32 + tid];
    else if (tid < 64) z2s[tid - 32] = z2f_[b * 32 + tid - 32];
    __syncthreads();
    const int kk = tid;  // 0..255
    const float* h1 = hw1 + layer * 8192 + kk;
    const float* h2 = hw2 + layer * 8192 + kk;
    float a = hb1[layer * 256 + kk];
    float c = hb2[layer * 256 + kk];
#pragma unroll
    for (int d = 0; d < 32; d++) {
        a = fmaf(z1s[d], h1[d * 256], a);
        c = fmaf(z2s[d], h2[d * 256], c);
    }
    a = fminf(fmaxf(a, -NORMC), NORMC);
    w_out[(size_t)b * 512 + layer * 256 + kk] = a + c;
}

// ---------------- apply: out = x1 -> (lin, w, lout) x2 ; + loss write ----------------
// 32 blocks x 256 thr: 8 samples/block, 32 lanes/sample.
__global__ __launch_bounds__(256) void k_apply(const float* __restrict__ x1,
                                               const float* __restrict__ w_in,
                                               const float* __restrict__ lin_w, const float* __restrict__ lin_b,
                                               const float* __restrict__ lout_w, const float* __restrict__ lout_b,
                                               const float* __restrict__ loss_sum, float* __restrict__ out) {
    __shared__ float linw[1024], loutw[1024], linb[32], loutb[64];
    __shared__ float wL[8][512];
    __shared__ float oc[8][32], t1s[8][16], t2s[8][16];
    const int tid = threadIdx.x;
    const int b0 = blockIdx.x * 8;
    {   // stage shared weights
        for (int p = tid; p < 1024; p += 256) { linw[p] = lin_w[p]; loutw[p] = lout_w[p]; }
        if (tid < 32) linb[tid] = lin_b[tid];
        if (tid >= 32 && tid < 96) loutb[tid - 32] = lout_b[tid - 32];
        // per-sample generated weights: 8 x 512 contiguous
        const float4* src = (const float4*)(w_in + (size_t)b0 * 512);
#pragma unroll
        for (int i = 0; i < 4; i++) {
            float4 v = src[tid + i * 256];
            ((float4*)&wL[0][0])[tid + i * 256] = v;
        }
        // init oc from x1
        float v = x1[b0 * 32 + tid];
        oc[tid >> 5][tid & 31] = v;
    }
    __syncthreads();
    const int s = tid >> 5, l = tid & 31;
#pragma unroll
    for (int i = 0; i < LL; i++) {
        if (l < 16) {
            float a = linb[i * 16 + l];
#pragma unroll
            for (int u = 0; u < 32; u++) a = fmaf(oc[s][u], linw[i * 512 + u * 16 + l], a);
            t1s[s][l] = a;
        }
        __syncthreads();
        if (l < 16) {
            float a = 0.f;
#pragma unroll
            for (int k = 0; k < 16; k++) a = fmaf(t1s[s][k], wL[s][i * 256 + k * 16 + l], a);
            t2s[s][l] = a;
        }
        __syncthreads();
        {
            float a = loutb[i * 32 + l];
#pragma unroll
            for (int k = 0; k < 16; k++) a = fmaf(t2s[s][k], loutw[i * 512 + k * 32 + l], a);
            oc[s][l] = a;
        }
        __syncthreads();
    }
    out[(size_t)(b0 + s) * 32 + l] = oc[s][l];
    if (blockIdx.x == 0 && tid == 0) out[B * UU] = loss_sum[0] * (1.0f / (float)(B * S * D));
}

extern "C" void kernel_launch(void* const* d_in, const int* in_sizes, int n_in,
                              void* d_out, int out_size, void* d_ws, size_t ws_size,
                              hipStream_t stream) {
    const float* x1     = (const float*)d_in[0];
    const float* z1     = (const float*)d_in[1];
    const float* z2     = (const float*)d_in[3];
    const float* embd   = (const float*)d_in[4];
    const float* dec_w1 = (const float*)d_in[5];
    const float* dec_b1 = (const float*)d_in[6];
    const float* dec_w2 = (const float*)d_in[7];
    const float* dec_b2 = (const float*)d_in[8];
    const float* i_wih  = (const float*)d_in[9];
    const float* i_whh  = (const float*)d_in[10];
    const float* i_bih  = (const float*)d_in[11];
    const float* i_bhh  = (const float*)d_in[12];
    const float* c_wih  = (const float*)d_in[13];
    const float* c_whh  = (const float*)d_in[14];
    const float* c_bih  = (const float*)d_in[15];
    const float* c_bhh  = (const float*)d_in[16];
    const float* im_w1  = (const float*)d_in[17];
    const float* im_b1  = (const float*)d_in[18];
    const float* im_w2  = (const float*)d_in[19];
    const float* im_b2  = (const float*)d_in[20];
    const float* cm_w1  = (const float*)d_in[21];
    const float* cm_b1  = (const float*)d_in[22];
    const float* cm_w2  = (const float*)d_in[23];
    const float* cm_b2  = (const float*)d_in[24];
    const float* hw1    = (const float*)d_in[25];
    const float* hb1    = (const float*)d_in[26];
    const float* hw2    = (const float*)d_in[27];
    const float* hb2    = (const float*)d_in[28];
    const float* lin_w  = (const float*)d_in[29];
    const float* lin_b  = (const float*)d_in[30];
    const float* lout_w = (const float*)d_in[31];
    const float* lout_b = (const float*)d_in[32];

    // workspace layout (floats)
    float* wsf      = (float*)d_ws;
    float* loss_sum = wsf;                       // 1 (pad to 64)
    float* tn       = wsf + 64;                  // VPAD = 10240
    float* pb_s     = wsf + 10304;               // 25600
    int*   pb_v     = (int*)(wsf + 35904);       // 25600
    float* z_recon  = wsf + 61504;               // 256*31*32 = 253952
    float* z1f      = wsf + 315456;              // 8192
    float* z2f      = wsf + 323648;              // 8192 -> 331840
    unsigned short* Eh = (unsigned short*)(wsf + 331840);  // VPAD*32 bf16
    unsigned short* El = (unsigned short*)(wsf + 495680);
    unsigned short* Qh = (unsigned short*)(wsf + 659520);  // NROWS*32 bf16 (dead after k_vq)
    unsigned short* Ql = (unsigned short*)(wsf + 864320);
    float* w_out    = (float*)Qh;                // 256*512 = 131072 f, reuses dead Qh region

    k_prep<<<(40000 + 4 * NROWS + 255) / 256, 256, 0, stream>>>(embd, z1, Eh, El, Qh, Ql, tn, loss_sum);
    k_vq<<<(NROWS / 32) * 2, 256, 0, stream>>>((const short*)Qh, (const short*)Ql,
                                               (const short*)Eh, (const short*)El, tn, pb_s, pb_v);
    k_gather<<<NROWS / 256, 256, 0, stream>>>(z2, embd, pb_s, pb_v, dec_w1, dec_b1,
                                              dec_w2, dec_b2, z_recon, loss_sum);
    k_gru<<<512, 128, 0, stream>>>(z_recon, z2, i_wih, i_whh, i_bih, i_bhh,
                                   c_wih, c_whh, c_bih, c_bhh,
                                   im_w1, im_b1, im_w2, im_b2,
                                   cm_w1, cm_b1, cm_w2, cm_b2, z1f, z2f);
    k_wgen<<<2 * B, 256, 0, stream>>>(z1f, z2f, hw1, hb1, hw2, hb2, w_out);
    k_apply<<<B / 8, 256, 0, stream>>>(x1, w_out, lin_w, lin_b, lout_w, lout_b,
                                       loss_sum, (float*)d_out);
}

// Round 4
// 245.570 us; speedup vs baseline: 3.1241x; 1.0306x over previous
//
#include <hip/hip_runtime.h>
#include <math.h>

#define B 256
#define S 50
#define D 32
#define V 10000
#define VPAD 10240
#define KK 16
#define HH 64
#define LL 2
#define UU 32
#define TT 30          // trigger_seq_length
#define NROWS (B*S)    // 12800
#define NORMC 0.01f
#define CH 256         // codes per LDS chunk in k_vq
#define NSLICE 8
#define SLICE_V 1280   // VPAD / NSLICE
#define VQ_RB 128      // rows per k_vq block

typedef __attribute__((ext_vector_type(8))) short bf16x8;
typedef __attribute__((ext_vector_type(4))) float f32x4;

__device__ __forceinline__ float sigmoidf_(float x) { return 1.0f / (1.0f + expf(-x)); }

__device__ __forceinline__ unsigned short f2bf(float x) {
    union { float f; unsigned int u; } a; a.f = x;
    unsigned int u = a.u;
    return (unsigned short)((u + 0x7FFFu + ((u >> 16) & 1u)) >> 16);  // RNE, inputs finite
}
__device__ __forceinline__ float bf2f(unsigned short h) {
    union { unsigned int u; float f; } a; a.u = ((unsigned int)h) << 16; return a.f;
}

__device__ __forceinline__ void gld16(void* lds, const void* g) {
    __builtin_amdgcn_global_load_lds(
        (const __attribute__((address_space(1))) unsigned int*)g,
        (__attribute__((address_space(3))) unsigned int*)lds, 16, 0, 0);
}
__device__ __forceinline__ void gld4(void* lds, const void* g) {
    __builtin_amdgcn_global_load_lds(
        (const __attribute__((address_space(1))) unsigned int*)g,
        (__attribute__((address_space(3))) unsigned int*)lds, 4, 0, 0);
}

// ---------------- prep: split fp32 -> (hi,lo) bf16; E padded to VPAD (zeros, tn=+inf);
// Q stores split of NEGATED z1 (so MFMA computes tn - q.t directly). Also zero loss.
__global__ __launch_bounds__(256) void k_prep(const float* __restrict__ embd,
                                              const float* __restrict__ z1,
                                              unsigned short* __restrict__ Eh, unsigned short* __restrict__ El,
                                              unsigned short* __restrict__ Qh, unsigned short* __restrict__ Ql,
                                              float* __restrict__ tn, float* __restrict__ loss_sum) {
    int gid = blockIdx.x * 256 + threadIdx.x;
    if (gid == 0) loss_sum[0] = 0.f;
    if (gid >= VPAD * 4 + 4 * NROWS) return;
    int isRow = (gid >= VPAD * 4);
    if (!isRow) {
        int item = gid >> 2, qd = gid & 3;
        unsigned short* dh = Eh + (size_t)item * D + qd * 8;
        unsigned short* dl = El + (size_t)item * D + qd * 8;
        if (item >= V) {   // pad codes: zero embedding, +inf tnorm -> never selected
            unsigned short z[8] = {0, 0, 0, 0, 0, 0, 0, 0};
            *(uint4*)dh = *(const uint4*)z;
            *(uint4*)dl = *(const uint4*)z;
            if (qd == 0) tn[item] = INFINITY;
            return;
        }
        const float* src = embd + (size_t)item * D + qd * 8;
        float4 x0 = *(const float4*)(src);
        float4 x1 = *(const float4*)(src + 4);
        float xs[8] = {x0.x, x0.y, x0.z, x0.w, x1.x, x1.y, x1.z, x1.w};
        unsigned short hv[8], lv[8];
        float ss = 0.f;
#pragma unroll
        for (int i = 0; i < 8; i++) {
            float x = xs[i];
            ss = fmaf(x, x, ss);
            unsigned short h = f2bf(x);
            hv[i] = h;
            lv[i] = f2bf(x - bf2f(h));
        }
        *(uint4*)dh = *(const uint4*)hv;
        *(uint4*)dl = *(const uint4*)lv;
        ss += __shfl_xor(ss, 1);
        ss += __shfl_xor(ss, 2);
        if (qd == 0) tn[item] = 0.5f * ss;
    } else {
        int g = gid - VPAD * 4;
        int item = g >> 2, qd = g & 3;
        const float* src = z1 + (size_t)item * D + qd * 8;
        unsigned short* dh = Qh + (size_t)item * D + qd * 8;
        unsigned short* dl = Ql + (size_t)item * D + qd * 8;
        float4 x0 = *(const float4*)(src);
        float4 x1 = *(const float4*)(src + 4);
        float xs[8] = {x0.x, x0.y, x0.z, x0.w, x1.x, x1.y, x1.z, x1.w};
        unsigned short hv[8], lv[8];
#pragma unroll
        for (int i = 0; i < 8; i++) {
            float x = -xs[i];   // negate: MFMA accumulates tn + (-q).t
            unsigned short h = f2bf(x);
            hv[i] = h;
            lv[i] = f2bf(x - bf2f(h));
        }
        *(uint4*)dh = *(const uint4*)hv;
        *(uint4*)dl = *(const uint4*)lv;
    }
}

// ---------------- VQ argmin via split-bf16 MFMA, XOR-swizzled LDS ----------------
// Grid: 100 row-groups (128 rows) x 8 V-slices (1280 codes). Block 256 thr = 4 waves;
// wave w -> rows w*32..w*32+31 (2 rowtiles), all 256 codes of each chunk.
__global__ __launch_bounds__(256) void k_vq(const short* __restrict__ Qh, const short* __restrict__ Ql,
                                            const short* __restrict__ Eh, const short* __restrict__ El,
                                            const float* __restrict__ tn,
                                            float* __restrict__ pb_s, int* __restrict__ pb_v) {
    __shared__ __attribute__((aligned(16))) short EhL[CH * 32];  // 16 KB
    __shared__ __attribute__((aligned(16))) short ElL[CH * 32];  // 16 KB
    __shared__ float tnL[CH];
    const int tid = threadIdx.x;
    const int wave = tid >> 6, lane = tid & 63;
    const int rg = blockIdx.x >> 3, slice = blockIdx.x & 7;
    const int row0 = rg * VQ_RB;
    const int quad = lane >> 4, c15 = lane & 15;
    const int swz = quad ^ ((c15 >> 1) & 3);            // reader swizzle (16B units)
    // A fragments: rows row0 + wave*32 + rt*16 + c15 (negated Q)
    const int ar0 = row0 + wave * 32 + c15;
    bf16x8 ah0 = *(const bf16x8*)(Qh + (size_t)ar0 * 32 + quad * 8);
    bf16x8 al0 = *(const bf16x8*)(Ql + (size_t)ar0 * 32 + quad * 8);
    bf16x8 ah1 = *(const bf16x8*)(Qh + (size_t)(ar0 + 16) * 32 + quad * 8);
    bf16x8 al1 = *(const bf16x8*)(Ql + (size_t)(ar0 + 16) * 32 + quad * 8);
    float best0[4], best1[4]; int bv0[4], bv1[4];
#pragma unroll
    for (int i = 0; i < 4; i++) {
        best0[i] = INFINITY; best1[i] = INFINITY;
        bv0[i] = 0x7fffffff; bv1[i] = 0x7fffffff;
    }
    const int vbeg = slice * SLICE_V;
    for (int c0 = 0; c0 < SLICE_V; c0 += CH) {
        __syncthreads();  // previous chunk consumed
        {   // stage 256 codes, swizzled: LDS chunk c holds global (code=c>>2, q=(c&3)^((c>>3)&3))
            const int sbS = (vbeg + c0) * 32;  // shorts
#pragma unroll
            for (int i = 0; i < 4; i++) {
                int c = wave * 256 + i * 64 + lane;
                int code = c >> 2;
                int q = (c & 3) ^ ((c >> 3) & 3);
                int srcOff = sbS + code * 32 + q * 8;   // shorts
                int dstOff = (wave * 256 + i * 64) * 8; // shorts (HW adds lane*16B)
                gld16(EhL + dstOff, Eh + srcOff);
                gld16(ElL + dstOff, El + srcOff);
            }
            gld4(tnL + wave * 64, tn + vbeg + c0 + wave * 64 + lane);
        }
        __syncthreads();  // staged data visible
#pragma unroll
        for (int t = 0; t < 16; t++) {
            const int code = t * 16 + c15;
            const int boff = code * 32 + swz * 8;       // shorts
            bf16x8 bh = *(const bf16x8*)(EhL + boff);
            bf16x8 bl = *(const bf16x8*)(ElL + boff);
            const float tnv = tnL[code];
            f32x4 acc0 = {tnv, tnv, tnv, tnv};
            f32x4 acc1 = {tnv, tnv, tnv, tnv};
            acc0 = __builtin_amdgcn_mfma_f32_16x16x32_bf16(ah0, bh, acc0, 0, 0, 0);
            acc1 = __builtin_amdgcn_mfma_f32_16x16x32_bf16(ah1, bh, acc1, 0, 0, 0);
            acc0 = __builtin_amdgcn_mfma_f32_16x16x32_bf16(al0, bh, acc0, 0, 0, 0);
            acc1 = __builtin_amdgcn_mfma_f32_16x16x32_bf16(al1, bh, acc1, 0, 0, 0);
            acc0 = __builtin_amdgcn_mfma_f32_16x16x32_bf16(ah0, bl, acc0, 0, 0, 0);
            acc1 = __builtin_amdgcn_mfma_f32_16x16x32_bf16(ah1, bl, acc1, 0, 0, 0);
            acc0 = __builtin_amdgcn_mfma_f32_16x16x32_bf16(al0, bl, acc0, 0, 0, 0);
            acc1 = __builtin_amdgcn_mfma_f32_16x16x32_bf16(al1, bl, acc1, 0, 0, 0);
            const int v = vbeg + c0 + code;             // pad codes carry tn=+inf
#pragma unroll
            for (int i = 0; i < 4; i++) {
                float s0 = acc0[i];
                if (s0 < best0[i]) { best0[i] = s0; bv0[i] = v; }
                float s1 = acc1[i];
                if (s1 < best1[i]) { best1[i] = s1; bv1[i] = v; }
            }
        }
    }
    // reduce across the 16 code-lanes (lane bits 0..3); rows (quad,i) preserved
#pragma unroll
    for (int m = 1; m <= 8; m <<= 1) {
#pragma unroll
        for (int i = 0; i < 4; i++) {
            float os = __shfl_xor(best0[i], m); int ov = __shfl_xor(bv0[i], m);
            if (os < best0[i] || (os == best0[i] && ov < bv0[i])) { best0[i] = os; bv0[i] = ov; }
            os = __shfl_xor(best1[i], m); ov = __shfl_xor(bv1[i], m);
            if (os < best1[i] || (os == best1[i] && ov < bv1[i])) { best1[i] = os; bv1[i] = ov; }
        }
    }
    if (c15 == 0) {
#pragma unroll
        for (int i = 0; i < 4; i++) {
            int r0 = row0 + wave * 32 + quad * 4 + i;        // rowtile 0
            pb_s[(size_t)r0 * NSLICE + slice] = best0[i];
            pb_v[(size_t)r0 * NSLICE + slice] = bv0[i];
            int r1 = r0 + 16;                                 // rowtile 1
            pb_s[(size_t)r1 * NSLICE + slice] = best1[i];
            pb_v[(size_t)r1 * NSLICE + slice] = bv1[i];
        }
    }
}

// ---------------- merge slices, gather z_emb, VQ loss, decoder (s<=TT) ----------------
// 400 blocks x 256 thr; 32 rows/block. Decoder h-parallel with LDS-staged weights.
__global__ __launch_bounds__(256) void k_gather(const float* __restrict__ z2,
                                                const float* __restrict__ embd,
                                                const float* __restrict__ pb_s,
                                                const int* __restrict__ pb_v,
                                                const float* __restrict__ dw1,
                                                const float* __restrict__ db1,
                                                const float* __restrict__ dw2,
                                                const float* __restrict__ db2,
                                                float* __restrict__ z_recon,
                                                float* __restrict__ loss_sum) {
    __shared__ float dw1L[2048];       // [d][h] d*64+h
    __shared__ float dw2L[2048];       // [h][d] h*32+d
    __shared__ float db1L[64], db2L[32];
    __shared__ int   vidL[32];
    __shared__ float zeL[32][33];      // [r][d] pad 33
    __shared__ float aL[32][65];       // [r][h] pad 65
    const int tid = threadIdx.x;
    const int row0 = blockIdx.x * 32;
    for (int p = tid; p < 2048; p += 256) { dw1L[p] = dw1[p]; dw2L[p] = dw2[p]; }
    if (tid < 64) db1L[tid] = db1[tid];
    if (tid >= 64 && tid < 96) db2L[tid - 64] = db2[tid - 64];
    if (tid < 32) {   // merge 8 slice partials (slices ascend in v; strict < keeps lowest v)
        const int r = row0 + tid;
        float bs = INFINITY; int bv = 0x7fffffff;
#pragma unroll
        for (int j = 0; j < NSLICE; j++) {
            float s = pb_s[(size_t)r * NSLICE + j];
            int   v = pb_v[(size_t)r * NSLICE + j];
            if (s < bs) { bs = s; bv = v; }
        }
        vidL[tid] = bv;
    }
    __syncthreads();
    const int r = tid >> 3, q = tid & 7;  // 32 rows x 8 groups
    {   // fetch z_emb rows (float4 per thread x2? 8 groups x 4 floats = 32)
        float4 e4 = *(const float4*)(embd + (size_t)vidL[r] * D + q * 4);
        zeL[r][q * 4 + 0] = e4.x; zeL[r][q * 4 + 1] = e4.y;
        zeL[r][q * 4 + 2] = e4.z; zeL[r][q * 4 + 3] = e4.w;
    }
    __syncthreads();
    {   // loss: thread handles 4 d's of its row
        const float* zp = z2 + (size_t)(row0 + r) * D + q * 4;
        float4 x4 = *(const float4*)zp;
        float d0 = x4.x - zeL[r][q * 4 + 0], d1 = x4.y - zeL[r][q * 4 + 1];
        float d2 = x4.z - zeL[r][q * 4 + 2], d3 = x4.w - zeL[r][q * 4 + 3];
        float ls = d0 * d0 + d1 * d1 + d2 * d2 + d3 * d3;
#pragma unroll
        for (int off = 32; off > 0; off >>= 1) ls += __shfl_down(ls, off);
        if ((tid & 63) == 0) atomicAdd(loss_sum, ls);
    }
    const int s = (row0 + r) % S;
    const bool dec = (s <= TT);
    // phase A: a[r][h] for h = q*8..q*8+7
    if (dec) {
#pragma unroll
        for (int j = 0; j < 8; j++) {
            int h = q * 8 + j;
            float a = db1L[h];
#pragma unroll
            for (int d = 0; d < 32; d++) a = fmaf(zeL[r][d], dw1L[d * 64 + h], a);
            aL[r][h] = (a >= 0.f) ? a : 0.1f * a;
        }
    }
    __syncthreads();
    // phase B: zr[d] for d = q*4..q*4+3
    if (dec) {
        const int b = (row0 + r) / S;
        float zr[4];
#pragma unroll
        for (int dd = 0; dd < 4; dd++) zr[dd] = db2L[q * 4 + dd];
        for (int h = 0; h < 64; h++) {
            float av = aL[r][h];
#pragma unroll
            for (int dd = 0; dd < 4; dd++) zr[dd] = fmaf(av, dw2L[h * 32 + q * 4 + dd], zr[dd]);
        }
        float4 o4 = make_float4(zr[0], zr[1], zr[2], zr[3]);
        *(float4*)(z_recon + (size_t)b * ((TT + 1) * D) + s * D + q * 4) = o4;
    }
}

// ---------------- GRU (31 steps) + output MLP; 512 blocks: [gru][sample] ----------------
__global__ __launch_bounds__(128) void k_gru(const float* __restrict__ z_recon,
                                             const float* __restrict__ z2,
                                             const float* __restrict__ i_wih, const float* __restrict__ i_whh,
                                             const float* __restrict__ i_bih, const float* __restrict__ i_bhh,
                                             const float* __restrict__ c_wih, const float* __restrict__ c_whh,
                                             const float* __restrict__ c_bih, const float* __restrict__ c_bhh,
                                             const float* __restrict__ im_w1, const float* __restrict__ im_b1,
                                             const float* __restrict__ im_w2, const float* __restrict__ im_b2,
                                             const float* __restrict__ cm_w1, const float* __restrict__ cm_b1,
                                             const float* __restrict__ cm_w2, const float* __restrict__ cm_b2,
                                             float* __restrict__ z1f, float* __restrict__ z2f) {
    const int tid = threadIdx.x;
    const int which = blockIdx.x >> 8;
    const int b = blockIdx.x & 255;
    const float* x; int xstride;
    const float *wih, *whh, *bih, *bhh, *w1, *b1, *w2, *b2; float* zf;
    if (which == 0) { x = z_recon; xstride = (TT + 1) * D; wih = i_wih; whh = i_whh; bih = i_bih; bhh = i_bhh; w1 = im_w1; b1 = im_b1; w2 = im_w2; b2 = im_b2; zf = z1f; }
    else            { x = z2;      xstride = S * D;        wih = c_wih; whh = c_whh; bih = c_bih; bhh = c_bhh; w1 = cm_w1; b1 = cm_b1; w2 = cm_w2; b2 = cm_b2; zf = z2f; }
    __shared__ float wihT[32][97];
    __shared__ float whhT[32][97];
    __shared__ float gi[TT + 1][96];
    __shared__ float xs[TT + 1][32];
    __shared__ float hsh[2][32];
    __shared__ float gh[96];
    __shared__ float bh2[96];
    __shared__ float af[32];
    for (int p = tid; p < 96 * 32; p += 128) {
        int e = p >> 5, d = p & 31;
        wihT[d][e] = wih[p];
        whhT[d][e] = whh[p];
    }
    for (int p = tid; p < (TT + 1) * D; p += 128) xs[p >> 5][p & 31] = x[(size_t)b * xstride + p];
    if (tid < 96) bh2[tid] = bhh[tid];
    if (tid < 32) hsh[0][tid] = 0.f;
    __syncthreads();
    for (int p = tid; p < (TT + 1) * 96; p += 128) {
        int s = p / 96, e = p % 96;
        float g0 = bih[e], g1 = 0.f;
#pragma unroll
        for (int d = 0; d < 16; d++) g0 = fmaf(xs[s][d], wihT[d][e], g0);
#pragma unroll
        for (int d = 16; d < 32; d++) g1 = fmaf(xs[s][d], wihT[d][e], g1);
        gi[s][e] = g0 + g1;
    }
    __syncthreads();
    for (int t = 0; t <= TT; t++) {
        const int cur = t & 1;
        if (tid < 96) {
            float g0 = bh2[tid], g1 = 0.f;
#pragma unroll
            for (int d = 0; d < 16; d++) g0 = fmaf(hsh[cur][d], whhT[d][tid], g0);
#pragma unroll
            for (int d = 16; d < 32; d++) g1 = fmaf(hsh[cur][d], whhT[d][tid], g1);
            gh[tid] = g0 + g1;
        }
        __syncthreads();
        if (tid < 32) {
            float rr = sigmoidf_(gi[t][tid] + gh[tid]);
            float zz = sigmoidf_(gi[t][tid + 32] + gh[tid + 32]);
            float nn = tanhf(gi[t][tid + 64] + rr * gh[tid + 64]);
            hsh[1 - cur][tid] = (1.f - zz) * nn + zz * hsh[cur][tid];
        }
        __syncthreads();
    }
    // final h in hsh[1] (t=TT=30: cur=0 -> wrote hsh[1])
    if (tid < 32) {
        float a = b1[tid];
#pragma unroll
        for (int d = 0; d < 32; d++) a = fmaf(hsh[1][d], w1[d * 32 + tid], a);
        af[tid] = tanhf(a);
    }
    __syncthreads();
    if (tid < 32) {
        float o = b2[tid];
#pragma unroll
        for (int d = 0; d < 32; d++) o = fmaf(af[d], w2[d * 32 + tid], o);
        zf[(size_t)b * 32 + tid] = o;
    }
}

// ---------------- hypernet weight-gen: w[b][p] = clip(z1f.hw1) + z2f.hw2 ----------------
__global__ __launch_bounds__(256) void k_wgen(const float* __restrict__ z1f_, const float* __restrict__ z2f_,
                                              const float* __restrict__ hw1, const float* __restrict__ hb1,
                                              const float* __restrict__ hw2, const float* __restrict__ hb2,
                                              float* __restrict__ w_out) {
    __shared__ float z1s[32], z2s[32];
    const int tid = threadIdx.x;
    const int b = blockIdx.x >> 1;
    const int layer = blockIdx.x & 1;
    if (tid < 32) z1s[tid] = z1f_[b * 32 + tid];
    else if (tid < 64) z2s[tid - 32] = z2f_[b * 32 + tid - 32];
    __syncthreads();
    const int kk = tid;  // 0..255
    const float* h1 = hw1 + layer * 8192 + kk;
    const float* h2 = hw2 + layer * 8192 + kk;
    float a = hb1[layer * 256 + kk];
    float c = hb2[layer * 256 + kk];
#pragma unroll
    for (int d = 0; d < 32; d++) {
        a = fmaf(z1s[d], h1[d * 256], a);
        c = fmaf(z2s[d], h2[d * 256], c);
    }
    a = fminf(fmaxf(a, -NORMC), NORMC);
    w_out[(size_t)b * 512 + layer * 256 + kk] = a + c;
}

// ---------------- apply: out = x1 -> (lin, w, lout) x2 ; + loss write ----------------
__global__ __launch_bounds__(256) void k_apply(const float* __restrict__ x1,
                                               const float* __restrict__ w_in,
                                               const float* __restrict__ lin_w, const float* __restrict__ lin_b,
                                               const float* __restrict__ lout_w, const float* __restrict__ lout_b,
                                               const float* __restrict__ loss_sum, float* __restrict__ out) {
    __shared__ float linw[1024], loutw[1024], linb[32], loutb[64];
    __shared__ float wL[8][512];
    __shared__ float oc[8][32], t1s[8][16], t2s[8][16];
    const int tid = threadIdx.x;
    const int b0 = blockIdx.x * 8;
    {
        for (int p = tid; p < 1024; p += 256) { linw[p] = lin_w[p]; loutw[p] = lout_w[p]; }
        if (tid < 32) linb[tid] = lin_b[tid];
        if (tid >= 32 && tid < 96) loutb[tid - 32] = lout_b[tid - 32];
        const float4* src = (const float4*)(w_in + (size_t)b0 * 512);
#pragma unroll
        for (int i = 0; i < 4; i++) {
            float4 v = src[tid + i * 256];
            ((float4*)&wL[0][0])[tid + i * 256] = v;
        }
        float v = x1[b0 * 32 + tid];
        oc[tid >> 5][tid & 31] = v;
    }
    __syncthreads();
    const int s = tid >> 5, l = tid & 31;
#pragma unroll
    for (int i = 0; i < LL; i++) {
        if (l < 16) {
            float a = linb[i * 16 + l];
#pragma unroll
            for (int u = 0; u < 32; u++) a = fmaf(oc[s][u], linw[i * 512 + u * 16 + l], a);
            t1s[s][l] = a;
        }
        __syncthreads();
        if (l < 16) {
            float a = 0.f;
#pragma unroll
            for (int k = 0; k < 16; k++) a = fmaf(t1s[s][k], wL[s][i * 256 + k * 16 + l], a);
            t2s[s][l] = a;
        }
        __syncthreads();
        {
            float a = loutb[i * 32 + l];
#pragma unroll
            for (int k = 0; k < 16; k++) a = fmaf(t2s[s][k], loutw[i * 512 + k * 32 + l], a);
            oc[s][l] = a;
        }
        __syncthreads();
    }
    out[(size_t)(b0 + s) * 32 + l] = oc[s][l];
    if (blockIdx.x == 0 && tid == 0) out[B * UU] = loss_sum[0] * (1.0f / (float)(B * S * D));
}

extern "C" void kernel_launch(void* const* d_in, const int* in_sizes, int n_in,
                              void* d_out, int out_size, void* d_ws, size_t ws_size,
                              hipStream_t stream) {
    const float* x1     = (const float*)d_in[0];
    const float* z1     = (const float*)d_in[1];
    const float* z2     = (const float*)d_in[3];
    const float* embd   = (const float*)d_in[4];
    const float* dec_w1 = (const float*)d_in[5];
    const float* dec_b1 = (const float*)d_in[6];
    const float* dec_w2 = (const float*)d_in[7];
    const float* dec_b2 = (const float*)d_in[8];
    const float* i_wih  = (const float*)d_in[9];
    const float* i_whh  = (const float*)d_in[10];
    const float* i_bih  = (const float*)d_in[11];
    const float* i_bhh  = (const float*)d_in[12];
    const float* c_wih  = (const float*)d_in[13];
    const float* c_whh  = (const float*)d_in[14];
    const float* c_bih  = (const float*)d_in[15];
    const float* c_bhh  = (const float*)d_in[16];
    const float* im_w1  = (const float*)d_in[17];
    const float* im_b1  = (const float*)d_in[18];
    const float* im_w2  = (const float*)d_in[19];
    const float* im_b2  = (const float*)d_in[20];
    const float* cm_w1  = (const float*)d_in[21];
    const float* cm_b1  = (const float*)d_in[22];
    const float* cm_w2  = (const float*)d_in[23];
    const float* cm_b2  = (const float*)d_in[24];
    const float* hw1    = (const float*)d_in[25];
    const float* hb1    = (const float*)d_in[26];
    const float* hw2    = (const float*)d_in[27];
    const float* hb2    = (const float*)d_in[28];
    const float* lin_w  = (const float*)d_in[29];
    const float* lin_b  = (const float*)d_in[30];
    const float* lout_w = (const float*)d_in[31];
    const float* lout_b = (const float*)d_in[32];

    // workspace layout (floats)
    float* wsf      = (float*)d_ws;
    float* loss_sum = wsf;                        // pad 64
    float* tn       = wsf + 64;                   // VPAD -> 10304
    float* pb_s     = wsf + 10304;                // NROWS*8 = 102400 -> 112704
    int*   pb_v     = (int*)(wsf + 112704);       // 102400 -> 215104
    unsigned short* Eh = (unsigned short*)(wsf + 215104);  // VPAD*32 shorts = 163840 f -> 378944
    unsigned short* El = (unsigned short*)(wsf + 378944);  // -> 542784
    unsigned short* Qh = (unsigned short*)(wsf + 542784);  // NROWS*32 shorts = 204800 f -> 747584
    unsigned short* Ql = (unsigned short*)(wsf + 747584);  // -> 952384
    float* z1f      = wsf + 952384;               // 8192 -> 960576
    float* z2f      = wsf + 960576;               // 8192 -> 968768 (~3.9 MB)
    float* z_recon  = (float*)Eh;                 // 253952 f, aliases Eh+El (dead after k_vq)
    float* w_out    = (float*)Qh;                 // 131072 f, aliases Qh (dead after k_vq)

    k_prep<<<(VPAD * 4 + 4 * NROWS + 255) / 256, 256, 0, stream>>>(embd, z1, Eh, El, Qh, Ql, tn, loss_sum);
    k_vq<<<(NROWS / VQ_RB) * NSLICE, 256, 0, stream>>>((const short*)Qh, (const short*)Ql,
                                                       (const short*)Eh, (const short*)El, tn, pb_s, pb_v);
    k_gather<<<NROWS / 32, 256, 0, stream>>>(z2, embd, pb_s, pb_v, dec_w1, dec_b1,
                                             dec_w2, dec_b2, z_recon, loss_sum);
    k_gru<<<512, 128, 0, stream>>>(z_recon, z2, i_wih, i_whh, i_bih, i_bhh,
                                   c_wih, c_whh, c_bih, c_bhh,
                                   im_w1, im_b1, im_w2, im_b2,
                                   cm_w1, cm_b1, cm_w2, cm_b2, z1f, z2f);
    k_wgen<<<2 * B, 256, 0, stream>>>(z1f, z2f, hw1, hb1, hw2, hb2, w_out);
    k_apply<<<B / 8, 256, 0, stream>>>(x1, w_out, lin_w, lin_b, lout_w, lout_b,
                                       loss_sum, (float*)d_out);
}